// Round 8
// baseline (220.067 us; speedup 1.0000x reference)
//
#include <hip/hip_runtime.h>
#include <math.h>

typedef _Float16 half_t;
typedef _Float16 halfx8 __attribute__((ext_vector_type(8)));
typedef _Float16 halfx4 __attribute__((ext_vector_type(4)));
typedef float floatx4 __attribute__((ext_vector_type(4)));
typedef float floatx16 __attribute__((ext_vector_type(16)));
typedef unsigned int uintx2 __attribute__((ext_vector_type(2)));
typedef unsigned int uintx4 __attribute__((ext_vector_type(4)));

typedef __attribute__((address_space(3))) void lds_t;
typedef const __attribute__((address_space(1))) void gmem_t;

static constexpr int kB = 2;
static constexpr int kLD = 2048;
static constexpr int kLM = 2048;
static constexpr int kD = 1024;
static constexpr int kH = 16;
static constexpr int kDH = 64;

__device__ __forceinline__ float exp2_fast(float x) {
#if __has_builtin(__builtin_amdgcn_exp2f)
  return __builtin_amdgcn_exp2f(x);
#else
  return exp2f(x);
#endif
}

__device__ __forceinline__ int sbfe1(int src, int pos) {
#if __has_builtin(__builtin_amdgcn_sbfe)
  return __builtin_amdgcn_sbfe(src, pos, 1);   // 0 or -1
#else
  return ((int)((unsigned)src << (31 - pos))) >> 31;
#endif
}

// ---------------------------------------------------------------------------
// 1) f32 -> f16 conversion of X_dec, X_enc, Wq, Wk, Wv; plus attention-mask
//    int -> bit-packed u32 table (kB * kLM / 32 = 128 words).
// ---------------------------------------------------------------------------
__global__ __launch_bounds__(256) void convert_all(
    const float* __restrict__ s0, const float* __restrict__ s1,
    const float* __restrict__ s2, const float* __restrict__ s3,
    const float* __restrict__ s4, const int* __restrict__ am,
    half_t* __restrict__ d0, half_t* __restrict__ d1,
    half_t* __restrict__ d2, half_t* __restrict__ d3, half_t* __restrict__ d4,
    unsigned int* __restrict__ maskbits)
{
  const size_t N0 = (size_t)kB * kLD * kD;
  const size_t N1 = N0 + (size_t)kB * kLM * kD;
  const size_t N2 = N1 + (size_t)kD * kD;
  const size_t N3 = N2 + (size_t)kD * kD;
  const size_t N4 = N3 + (size_t)kD * kD;
  size_t idx = ((size_t)blockIdx.x * blockDim.x + threadIdx.x) * 4;
  if (idx >= N4) {  // bit-pack the attention mask: one u32 per thread
    const size_t wi = (idx - N4) >> 2;
    if (wi >= (size_t)(kB * kLM / 32)) return;
    const int* src = am + wi * 32;
    unsigned int wbits = 0;
#pragma unroll
    for (int j = 0; j < 32; ++j) wbits |= (src[j] ? 1u : 0u) << j;
    maskbits[wi] = wbits;
    return;
  }
  const float* s; half_t* d; size_t off;
  if (idx < N0)      { s = s0; d = d0; off = idx; }
  else if (idx < N1) { s = s1; d = d1; off = idx - N0; }
  else if (idx < N2) { s = s2; d = d2; off = idx - N1; }
  else if (idx < N3) { s = s3; d = d3; off = idx - N2; }
  else               { s = s4; d = d4; off = idx - N3; }
  float4 v = *(const float4*)(s + off);
  halfx4 hv;
  hv[0] = (half_t)v.x; hv[1] = (half_t)v.y; hv[2] = (half_t)v.z; hv[3] = (half_t)v.w;
  *(halfx4*)(d + off) = hv;
}

// ---------------------------------------------------------------------------
// 2) Fused QKV projection GEMM (m97 structure). Q scaled by 0.125*log2(e).
//    Mode 2 (V) swaps MFMA operands to produce C^T directly -> coalesced
//    32B-chunk stores into vtbuf[bh][dv][kv] (no 2B scatter).
// ---------------------------------------------------------------------------
__global__ __launch_bounds__(256, 2) void qkv_gemm(
    const half_t* __restrict__ xdec, const half_t* __restrict__ xenc,
    const half_t* __restrict__ wq, const half_t* __restrict__ wk,
    const half_t* __restrict__ wv,
    const float* __restrict__ bq, const float* __restrict__ bk,
    const float* __restrict__ bv,
    half_t* __restrict__ qbuf, half_t* __restrict__ kbuf,
    half_t* __restrict__ vtbuf)
{
  const int mode = blockIdx.z;
  const half_t* Ag = (mode == 0) ? xdec : xenc;
  const half_t* Bg = (mode == 0) ? wq : (mode == 1) ? wk : wv;
  const float* bias = (mode == 0) ? bq : (mode == 1) ? bk : bv;

  __shared__ alignas(16) half_t Alds[128 * 64];
  __shared__ alignas(16) half_t Blds[128 * 64];

  const int m0 = blockIdx.x * 128;
  const int n0 = blockIdx.y * 128;
  const int tid = threadIdx.x;
  const int lane = tid & 63;
  const int wid = tid >> 6;
  const int wr = wid >> 1, wc = wid & 1;
  const int l15 = lane & 15, lhi = lane >> 4;

  floatx4 acc[4][4] = {};

  for (int k0 = 0; k0 < kD; k0 += 64) {
    __syncthreads();
#pragma unroll
    for (int i = 0; i < 4; ++i) {
      const int ob = wid * 4096 + i * 1024;
      const int lo = ob + lane * 16;
      const int row = lo >> 7;
      const int colh = (lo & 127) >> 1;
      const half_t* ga = Ag + (size_t)(m0 + row) * kD + k0 + colh;
      const half_t* gb = Bg + (size_t)(n0 + row) * kD + k0 + colh;
      __builtin_amdgcn_global_load_lds((gmem_t*)ga, (lds_t*)((char*)Alds + ob), 16, 0, 0);
      __builtin_amdgcn_global_load_lds((gmem_t*)gb, (lds_t*)((char*)Blds + ob), 16, 0, 0);
    }
    __syncthreads();

#pragma unroll
    for (int ks = 0; ks < 2; ++ks) {
      halfx8 af[4], bf[4];
#pragma unroll
      for (int mt = 0; mt < 4; ++mt)
        af[mt] = *(const halfx8*)(Alds + (wr * 64 + mt * 16 + l15) * 64 + ks * 32 + lhi * 8);
#pragma unroll
      for (int nt = 0; nt < 4; ++nt)
        bf[nt] = *(const halfx8*)(Blds + (wc * 64 + nt * 16 + l15) * 64 + ks * 32 + lhi * 8);
      if (mode != 2) {
#pragma unroll
        for (int mt = 0; mt < 4; ++mt)
#pragma unroll
          for (int nt = 0; nt < 4; ++nt)
            acc[mt][nt] = __builtin_amdgcn_mfma_f32_16x16x32_f16(af[mt], bf[nt], acc[mt][nt], 0, 0, 0);
      } else {  // swapped: C^T, row = n (dv), col = m (kv)
#pragma unroll
        for (int mt = 0; mt < 4; ++mt)
#pragma unroll
          for (int nt = 0; nt < 4; ++nt)
            acc[mt][nt] = __builtin_amdgcn_mfma_f32_16x16x32_f16(bf[nt], af[mt], acc[mt][nt], 0, 0, 0);
      }
    }
  }

  if (mode != 2) {
#pragma unroll
    for (int nt = 0; nt < 4; ++nt) {
      const int n = n0 + wc * 64 + nt * 16 + l15;
      const float bb = bias[n];
      const int h = n >> 6, dv = n & 63;
#pragma unroll
      for (int mt = 0; mt < 4; ++mt) {
#pragma unroll
        for (int r = 0; r < 4; ++r) {
          const int m = m0 + wr * 64 + mt * 16 + lhi * 4 + r;
          const int b = m >> 11, rowl = m & 2047;
          float v = acc[mt][nt][r] + bb;
          if (mode == 0) {
            v *= 0.18033688011112042f;  // (1/sqrt(64)) * log2(e)
            qbuf[((size_t)(b * kH + h) * kLD + rowl) * kDH + dv] = (half_t)v;
          } else {
            kbuf[((size_t)(b * kH + h) * kLM + rowl) * kDH + dv] = (half_t)v;
          }
        }
      }
    }
  } else {
#pragma unroll
    for (int nt = 0; nt < 4; ++nt) {
      // rows of C^T: n (head dim), 4 per lane via lhi*4 + r
      const float4 bb4 = *(const float4*)(bias + n0 + wc * 64 + nt * 16 + lhi * 4);
#pragma unroll
      for (int mt = 0; mt < 4; ++mt) {
        const int m = m0 + wr * 64 + mt * 16 + l15;  // kv, contiguous in l15
        const int b = m >> 11, rowl = m & 2047;
#pragma unroll
        for (int r = 0; r < 4; ++r) {
          const int n = n0 + wc * 64 + nt * 16 + lhi * 4 + r;
          const int h = n >> 6, dv = n & 63;
          float v = acc[mt][nt][r] + ((const float*)&bb4)[r];
          vtbuf[((size_t)(b * kH + h) * kDH + dv) * kLM + rowl] = (half_t)v;
        }
      }
    }
  }
}

// ---------------------------------------------------------------------------
// 3) Flash attention, KVBLK=32, double-buffered LDS, ONE barrier per tile
//    (T3-minimum 2-phase: stage(next) -> compute(cur) -> barrier).
//    In-block KV-split (pair p covers kv [p*1024,(p+1)*1024)); swapped QK^T
//    in-register softmax; bit-mask via uniform scalar word + sbfe/AND on P;
//    defer-max (T13, raw-max variant); cvt_pkrtz+permlane P-pack.
// ---------------------------------------------------------------------------
__global__ __launch_bounds__(256) void attn_kernel(
    const half_t* __restrict__ qbuf, const half_t* __restrict__ kbuf,
    const half_t* __restrict__ vtbuf, const unsigned int* __restrict__ maskbits,
    const int* __restrict__ hmask, float* __restrict__ out)
{
  // XCD swizzle: 128 consecutive blocks (4 bh) per XCD
  const int x = blockIdx.x;
  const int ordered = (x & 7) * 128 + (x >> 3);
  const int bh = ordered >> 5, qt = ordered & 31;
  const int b = bh >> 4, h = bh & 15;

  const int tid = threadIdx.x;
  const int lane = tid & 63;
  const int wid = tid >> 6;
  const int p = wid >> 1;    // kv-half (0/1)
  const int w = wid & 1;     // wave within pair = q-group = staging half
  const int ql = lane & 31;
  const int hi = lane >> 5;

  __shared__ alignas(16) char smem[33 * 1024];
  char* Kb = smem + p * 16384;          // K dbuf: 2 x 4KB ([32 kv][64 d], swz)
  char* Vb = smem + p * 16384 + 8192;   // V dbuf: 2 x 4KB ([64 dv][32 kv], swz)
  float* mlds = (float*)(smem + 32768); // [2][m|l][64 q]

  const half_t* kbase = kbuf + (size_t)bh * (kLM * kDH) + (size_t)p * 1024 * kDH;
  const half_t* vtbase = vtbuf + (size_t)bh * (kDH * kLM) + p * 1024;
  const unsigned int* mwptr = maskbits + b * 64 + p * 32;

  // staging source swizzle (pre-swizzled global addr; LDS dest linear)
  const int kl_row = lane >> 3;                 // K: 8 rows/issue, 128B rows
  const int k_srcoff = ((lane & 7) ^ kl_row) * 8;
  const int vl_row = lane >> 2;                 // V: 16 rows/issue, 64B rows
  const int v_srcoff = ((lane & 3) ^ (vl_row & 3)) * 8;

  auto STAGE = [&](char* Kdst, char* Vdst, int kv0s) {
#pragma unroll
    for (int i = 0; i < 2; ++i) {
      __builtin_amdgcn_global_load_lds(
          (gmem_t*)(kbase + (size_t)(kv0s + w * 16 + i * 8 + kl_row) * kDH + k_srcoff),
          (lds_t*)(Kdst + w * 2048 + i * 1024), 16, 0, 0);
      __builtin_amdgcn_global_load_lds(
          (gmem_t*)(vtbase + (size_t)(w * 32 + i * 16 + vl_row) * kLM + kv0s + v_srcoff),
          (lds_t*)(Vdst + w * 2048 + i * 1024), 16, 0, 0);
    }
  };

  const int qg = qt * 64 + w * 32 + ql;  // global q row
  halfx8 qf[4];
#pragma unroll
  for (int ks = 0; ks < 4; ++ks)
    qf[ks] = *(const halfx8*)(qbuf + ((size_t)bh * kLD + qg) * kDH + ks * 16 + hi * 8);

  floatx16 ctx0 = {}, ctx1 = {};
  float m_run = -1e30f, l_run = 0.0f;

  // prologue: stage tile 0 into buffer 0; barrier drains vmcnt
  STAGE(Kb, Vb, 0);
  unsigned int maskw = mwptr[0];
  __syncthreads();

#pragma unroll 1
  for (int t = 0; t < 32; ++t) {
    const int kv0 = t * 32;
    char* Kc = Kb + (t & 1) * 4096;
    char* Vc = Vb + (t & 1) * 4096;
    if (t < 31) STAGE(Kb + ((t & 1) ^ 1) * 4096, Vb + ((t & 1) ^ 1) * 4096, kv0 + 32);
    const unsigned int mw = maskw;
    if (t < 31) maskw = mwptr[t + 1];

    // S^T = K · Q^T (swapped operands), one 32x32 tile
    floatx16 S = {};
#pragma unroll
    for (int ks = 0; ks < 4; ++ks) {
      const int off = ql * 128 + ((ks * 32 + hi * 16) ^ ((ql & 7) << 4));
      halfx8 kf = *(const halfx8*)(Kc + off);
      S = __builtin_amdgcn_mfma_f32_32x32x16_f16(kf, qf[ks], S, 0, 0, 0);
    }

    // tree max over RAW scores (masked entries only inflate m -> harmless)
    float m8[8];
#pragma unroll
    for (int i = 0; i < 8; ++i) m8[i] = fmaxf(S[i], S[i + 8]);
#pragma unroll
    for (int i = 0; i < 4; ++i) m8[i] = fmaxf(m8[i], m8[i + 4]);
    float mx = fmaxf(fmaxf(m8[0], m8[1]), fmaxf(m8[2], m8[3]));
    mx = fmaxf(mx, __shfl_xor(mx, 32));

    // T13 defer-max (exp2 units)
    if (!__all(mx <= m_run + 8.0f)) {
      const float mn = fmaxf(m_run, mx);
      const float sc = exp2_fast(m_run - mn);
      m_run = mn;
      l_run *= sc;
#pragma unroll
      for (int i = 0; i < 16; ++i) { ctx0[i] *= sc; ctx1[i] *= sc; }
    }

    // P = exp2(S - m) with bit-mask zeroing (sbfe -> 0/-1, AND)
    const int vrot = (int)(mw >> (hi * 4));
#pragma unroll
    for (int i = 0; i < 16; ++i) {
      float e = exp2_fast(S[i] - m_run);
      const int mb = sbfe1(vrot, (i & 3) + 8 * (i >> 2));
      S[i] = __builtin_bit_cast(float, __builtin_bit_cast(int, e) & mb);
    }
    // tree sum
    float s8[8];
#pragma unroll
    for (int i = 0; i < 8; ++i) s8[i] = S[i] + S[i + 8];
#pragma unroll
    for (int i = 0; i < 4; ++i) s8[i] += s8[i + 4];
    float ps = (s8[0] + s8[1]) + (s8[2] + s8[3]);
    ps += __shfl_xor(ps, 32);
    l_run += ps;

    // pack P^T into PV B-fragments: cvt_pkrtz + permlane32_swap
    halfx8 pb[2];
#pragma unroll
    for (int sl = 0; sl < 2; ++sl) {
      const int rA = sl * 8;
      unsigned wa = __builtin_bit_cast(unsigned, __builtin_amdgcn_cvt_pkrtz(S[rA + 0], S[rA + 1]));
      unsigned wb = __builtin_bit_cast(unsigned, __builtin_amdgcn_cvt_pkrtz(S[rA + 2], S[rA + 3]));
      unsigned wc = __builtin_bit_cast(unsigned, __builtin_amdgcn_cvt_pkrtz(S[rA + 4], S[rA + 5]));
      unsigned wd = __builtin_bit_cast(unsigned, __builtin_amdgcn_cvt_pkrtz(S[rA + 6], S[rA + 7]));
      uintx2 u1 = __builtin_amdgcn_permlane32_swap(wa, wc, false, false);
      uintx2 u2 = __builtin_amdgcn_permlane32_swap(wb, wd, false, false);
      uintx4 u;
      u[0] = u1[0]; u[1] = u2[0]; u[2] = u1[1]; u[3] = u2[1];
      pb[sl] = __builtin_bit_cast(halfx8, u);
    }

    // ctx^T += V^T · P^T  (2 dv-subtiles x 2 kv-slices)
#pragma unroll
    for (int sl = 0; sl < 2; ++sl) {
      const int chunk = ((sl * 2 + hi) << 4) ^ ((ql & 3) << 4);
      halfx8 vf0 = *(const halfx8*)(Vc + ql * 64 + chunk);
      ctx0 = __builtin_amdgcn_mfma_f32_32x32x16_f16(vf0, pb[sl], ctx0, 0, 0, 0);
      halfx8 vf1 = *(const halfx8*)(Vc + (32 + ql) * 64 + chunk);
      ctx1 = __builtin_amdgcn_mfma_f32_32x32x16_f16(vf1, pb[sl], ctx1, 0, 0, 0);
    }

    __syncthreads();  // drains my stage loads (vmcnt 0) + separates buf reuse
  }

  // ---- in-block combine of the two kv-halves (overlay O on KV LDS) ----
  {
    float* Op = (float*)(smem + p * 16384);  // [64 q][64 dv], swz
    const int q_local = w * 32 + ql;
#pragma unroll
    for (int g = 0; g < 4; ++g) {
#pragma unroll
      for (int pr = 0; pr < 2; ++pr) {
        const int r = g * 4 + pr * 2;
        const int dv0 = pr * 2 + 8 * g + 4 * hi;
        const int off0 = (q_local * 256 + dv0 * 4) ^ ((q_local & 7) << 4);
        *(float2*)((char*)Op + off0) = make_float2(ctx0[r], ctx0[r + 1]);
        const int off1 = (q_local * 256 + (dv0 + 32) * 4) ^ ((q_local & 7) << 4);
        *(float2*)((char*)Op + off1) = make_float2(ctx1[r], ctx1[r + 1]);
      }
    }
    if (hi == 0) {
      mlds[p * 128 + q_local] = m_run;
      mlds[p * 128 + 64 + q_local] = l_run;
    }
  }
  __syncthreads();

#pragma unroll
  for (int it = 0; it < 4; ++it) {
    const int idx = it * 256 + tid;
    const int q = idx >> 4, c4 = idx & 15;
    const int off = (q * 256 + c4 * 16) ^ ((q & 7) << 4);
    float4 o0 = *(const float4*)(smem + off);
    float4 o1 = *(const float4*)(smem + 16384 + off);
    const float m0 = mlds[q], l0 = mlds[64 + q];
    const float m1 = mlds[128 + q], l1 = mlds[192 + q];
    const float mm = fmaxf(m0, m1);
    float w0 = exp2_fast(m0 - mm), w1 = exp2_fast(m1 - mm);
    const int qglob = qt * 64 + q;
    const float inv = (hmask[b * kLD + qglob] ? 0.0f : 1.0f) / (l0 * w0 + l1 * w1);
    w0 *= inv; w1 *= inv;
    float4 o;
    o.x = o0.x * w0 + o1.x * w1;
    o.y = o0.y * w0 + o1.y * w1;
    o.z = o0.z * w0 + o1.z * w1;
    o.w = o0.w * w0 + o1.w * w1;
    *(float4*)(out + (((size_t)(b * kLD + qglob)) << 10) + h * 64 + c4 * 4) = o;
  }
}

// ---------------------------------------------------------------------------
extern "C" void kernel_launch(void* const* d_in, const int* in_sizes, int n_in,
                              void* d_out, int out_size, void* d_ws, size_t ws_size,
                              hipStream_t stream)
{
  const float* hs   = (const float*)d_in[0];
  const float* ehs  = (const float*)d_in[1];
  const int*   am   = (const int*)d_in[2];
  const int*   hm   = (const int*)d_in[3];
  const float* Wq   = (const float*)d_in[4];
  const float* bq   = (const float*)d_in[5];
  const float* Wk   = (const float*)d_in[6];
  const float* bk   = (const float*)d_in[7];
  const float* Wv   = (const float*)d_in[8];
  const float* bv   = (const float*)d_in[9];
  float* out = (float*)d_out;

  char* ws = (char*)d_ws;
  half_t* xdec_h = (half_t*)(ws);
  half_t* xenc_h = (half_t*)(ws + (8ull << 20));
  half_t* wq_h   = (half_t*)(ws + (16ull << 20));
  half_t* wk_h   = (half_t*)(ws + (18ull << 20));
  half_t* wv_h   = (half_t*)(ws + (20ull << 20));
  half_t* q_buf  = (half_t*)(ws + (22ull << 20));
  half_t* k_buf  = (half_t*)(ws + (30ull << 20));
  half_t* vt_buf = (half_t*)(ws + (38ull << 20));
  unsigned int* maskbits = (unsigned int*)(ws + (46ull << 20));

  convert_all<<<11265, 256, 0, stream>>>(hs, ehs, Wq, Wk, Wv, am,
                                         xdec_h, xenc_h, wq_h, wk_h, wv_h, maskbits);
  qkv_gemm<<<dim3(32, 8, 3), 256, 0, stream>>>(xdec_h, xenc_h, wq_h, wk_h, wv_h,
                                               bq, bk, bv, q_buf, k_buf, vt_buf);
  attn_kernel<<<1024, 256, 0, stream>>>(q_buf, k_buf, vt_buf, maskbits, hm, out);
}